// Round 4
// baseline (317.890 us; speedup 1.0000x reference)
//
#include <hip/hip_runtime.h>
#include <hip/hip_bf16.h>

typedef unsigned short u16;
typedef __attribute__((ext_vector_type(8))) short short8;
typedef __bf16 bf16x8 __attribute__((ext_vector_type(8)));
typedef __attribute__((ext_vector_type(4))) float float4v;
typedef __attribute__((ext_vector_type(4))) unsigned int uint4v;

#define BB 2
#define AA 512
#define TT 512
#define FF 128
#define NRBF 25

// static device scratch (no assumptions about ws_size)
__device__ float g_y[BB * AA * FF];
__device__ int   g_dtype;   // 0 = bf16 buffers, 1 = fp32 buffers

__device__ __forceinline__ float bf2f(u16 u) {
    unsigned int v = ((unsigned int)u) << 16;
    return __builtin_bit_cast(float, v);
}
__device__ __forceinline__ u16 f2bf(float f) {
    unsigned int u = __builtin_bit_cast(unsigned int, f);
    u += 0x7fffu + ((u >> 16) & 1u);   // RNE
    return (u16)(u >> 16);
}
// Dekker-style split: v == bf2f(h) + bf2f(l) to ~2^-17 relative.
__device__ __forceinline__ void split2(float v, u16& h, u16& l) {
    h = f2bf(v);
    l = f2bf(v - bf2f(h));
}
template<bool F32>
__device__ __forceinline__ float loadf(const void* p, int i) {
    return F32 ? ((const float*)p)[i] : bf2f(((const u16*)p)[i]);
}
// shifted softplus via raw HW transcendentals (v_exp_f32 / v_log_f32):
// ssp(v) = max(v,0) + ln2*log2(1 + 2^(-|v|*log2e)) - ln2
__device__ __forceinline__ float ssp(float v) {
    float a = fabsf(v);
    float e = __builtin_amdgcn_exp2f(a * -1.44269504088896f);   // e^-|v|
    float l = __builtin_amdgcn_logf(1.0f + e);                  // log2(1+e^-|v|)
    return fmaxf(v, 0.0f) + fmaf(0.69314718055995f, l, -0.69314718055995f);
}
__device__ __forceinline__ float4v mfma16(short8 a, short8 b, float4v c) {
    return __builtin_amdgcn_mfma_f32_16x16x32_bf16(
        __builtin_bit_cast(bf16x8, a), __builtin_bit_cast(bf16x8, b), c, 0, 0, 0);
}

// ---- dtype detector (round-3 proven single-wave form, race-free) ----------
__global__ __launch_bounds__(64) void k_detect(const void* r_raw) {
    const u16* p = (const u16*)r_raw;
    const int l = threadIdx.x;            // 0..63, one wave
    int sign = 0, zeros = 0;
#pragma unroll
    for (int i = 0; i < 8; ++i) {
        u16 v = p[2 * (l * 8 + i)];
        sign  += (v >> 15);
        zeros += (v == 0);
    }
#pragma unroll
    for (int off = 1; off < 64; off <<= 1) {
        sign  += __shfl_xor(sign, off);
        zeros += __shfl_xor(zeros, off);
    }
    if (l == 0) g_dtype = (sign || zeros > 400) ? 1 : 0;
}

// ---------------- kernel 1: y[b,a,f] = sum_i x[b,a,i] * Win[i,f]  (fp32 out) --
template<bool F32>
__global__ __launch_bounds__(128) void k_in2f(const void* __restrict__ x,
                                              const void* __restrict__ Win) {
    if (g_dtype != (F32 ? 1 : 0)) return;
    int ba = blockIdx.x;
    int o  = threadIdx.x;
    __shared__ float sx[FF];
    sx[o] = loadf<F32>(x, ba * FF + o);
    __syncthreads();
    float s = 0.f;
#pragma unroll 8
    for (int i = 0; i < FF; ++i)
        s = fmaf(sx[i], loadf<F32>(Win, i * FF + o), s);
    g_y[ba * FF + o] = s;
}

// ---------------- kernel 2: fused filter-net + gather-product + output -------
// BARRIER-FREE main loop: each of the 4 waves owns 128 t-rows (8 groups of 16)
// and runs the full pipeline privately. Round-3's lockstep version (3 barriers
// x 32 tiles) measured OccupancyPercent ~22% with 16 waves resident = waves
// parked at barriers; MfmaUtil 14 / VALUBusy 31 / HBM 3% -> pure serialization.
// Numerics identical to round-3 (split-bf16 MFMA, absmax 0.0625 = output
// rounding floor). Fragment layouts carried over verbatim:
//   A-frag:  lane(lm,lq) elem j = M[row=lm][k=lq*8+j]
//   B-frag:  lane(lm,lq) elem j = W[k=lq*8+j][col=nt*16+lm]
//   C tile:  lane(lm,lq) reg r  = D[row=lq*4+r][col=nt*16+lm]
// Per-wave LDS H1 scratch ([t][c], u32 = hi|lo packed, stride 132 for banks +
// 16B alignment); Wf2 pre-permuted once into LDS fragments (1 barrier total).
template<bool F32>
__global__ __launch_bounds__(256, 2) void k_main(
    const void* __restrict__ r_ij, const void* __restrict__ mask,
    const void* __restrict__ Wf1,  const void* __restrict__ bf1,
    const void* __restrict__ Wf2,  const void* __restrict__ bf2_,
    const void* __restrict__ Wout, const void* __restrict__ bout,
    const int* __restrict__ nbrj,  const int* __restrict__ nbrk,
    void* __restrict__ out)
{
    if (g_dtype != (F32 ? 1 : 0)) return;
    const int ba  = blockIdx.x;           // (b,a) flat
    const int tid = threadIdx.x;
    const int w   = tid >> 6;             // wave 0..3 -> owns t-rows [128w,128w+128)
    const int l   = tid & 63;
    const int lm  = l & 15;
    const int lq  = l >> 4;

    // [kk][nt][lane][j] pre-permuted Wf2 B-fragments, 16B/lane -> ds_read_b128
    __shared__ __align__(16) u16 sW2h[4 * 8 * 64 * 8];             // 32 KB
    __shared__ __align__(16) u16 sW2l[F32 ? 4 * 8 * 64 * 8 : 16];  // F32 path only
    // per-wave H1 scratch: [wave][t=16][c=128+pad] u32 = (hi16|lo16)
    __shared__ __align__(16) unsigned int sH1[4][16][132];         // 33 KB
    __shared__ float sAccW[4][FF];
    __shared__ float sA[FF];

    // ---- one-time: permute Wf2 into B-fragment layout (coalesced reads) ----
    for (int idx = tid; idx < FF * FF; idx += 256) {
        const int k = idx >> 7, n = idx & 127;
        const int kk = k >> 5, lq2 = (k >> 3) & 3, j = k & 7;
        const int nt = n >> 4, lmn = n & 15;
        const int dst = (((kk << 3) + nt) << 9) + ((lq2 * 16 + lmn) << 3) + j;
        u16 h, lo; split2(loadf<F32>(Wf2, idx), h, lo);
        sW2h[dst] = h;
        if constexpr (F32) sW2l[dst] = lo;
    }

    // ---- Wf1 B-fragments (8 N-tiles) + biases in registers ----
    short8 fW1h[8], fW1l[8];
    float  bf1v[8], bf2v[8];
#pragma unroll
    for (int nt = 0; nt < 8; ++nt) {
        const int n = nt * 16 + lm;
        short8 vh, vl;
#pragma unroll
        for (int j = 0; j < 8; ++j) {
            const int k = lq * 8 + j;
            float wv = (k < NRBF) ? loadf<F32>(Wf1, k * FF + n) : 0.f;
            u16 h, lo; split2(wv, h, lo);
            vh[j] = (short)h; vl[j] = (short)lo;
        }
        fW1h[nt] = vh;
        if constexpr (F32) fW1l[nt] = vl;
        bf1v[nt] = loadf<F32>(bf1, n);
        bf2v[nt] = loadf<F32>(bf2_, n);
    }
    __syncthreads();   // sW2 ready; ONLY barrier before the epilogue

    const float* yb = g_y + (ba >> 9) * (AA * FF);
    const float4v zero = {0.f, 0.f, 0.f, 0.f};
    float Cacc[8] = {0.f, 0.f, 0.f, 0.f, 0.f, 0.f, 0.f, 0.f};

    for (int g = 0; g < 8; ++g) {
        const int rowg = ba * TT + w * 128 + g * 16;   // global row of this group

        // ---- phase A: A-frag direct from global, 8 MFMAs -> H1 in regs ----
        short8 aRh, aRl;
#pragma unroll
        for (int j = 0; j < 8; ++j) {
            const int k = lq * 8 + j;
            const int ridx = (k < NRBF) ? ((rowg + lm) * NRBF + k) : 0;
            if constexpr (F32) {
                float v = (k < NRBF) ? ((const float*)r_ij)[ridx] : 0.f;
                u16 h, lo; split2(v, h, lo);
                aRh[j] = (short)h; aRl[j] = (short)lo;
            } else {
                aRh[j] = (k < NRBF) ? (short)((const u16*)r_ij)[ridx] : (short)0;
            }
        }
        float4v c1[8];
#pragma unroll
        for (int nt = 0; nt < 8; ++nt) c1[nt] = mfma16(aRh, fW1h[nt], zero);
        if constexpr (F32) {
#pragma unroll
            for (int nt = 0; nt < 8; ++nt) {
                c1[nt] = mfma16(aRl, fW1h[nt], c1[nt]);
                c1[nt] = mfma16(aRh, fW1l[nt], c1[nt]);
            }
        }

        // ---- ssp + hi/lo pack -> wave-private LDS (no barrier: same wave) ----
#pragma unroll
        for (int nt = 0; nt < 8; ++nt) {
#pragma unroll
            for (int r = 0; r < 4; ++r) {
                const float h1 = ssp(c1[nt][r] + bf1v[nt]);
                const unsigned int u  = __builtin_bit_cast(unsigned int, h1);
                const unsigned int t2 = u + 0x7fffu + ((u >> 16) & 1u);
                const unsigned int hb = t2 & 0xffff0000u;           // hi = RNE bf16
                const float rem = h1 - __builtin_bit_cast(float, hb);
                const unsigned int pk =
                    hb | (__builtin_bit_cast(unsigned int, rem) >> 16);  // lo trunc
                sH1[w][lq * 4 + r][nt * 16 + lm] = pk;
            }
        }

        // ---- phase B: H2 = H1 @ Wf2 (split-bf16), B-frags from LDS ----
        float4v c2[8];
#pragma unroll
        for (int nt = 0; nt < 8; ++nt) c2[nt] = zero;
#pragma unroll
        for (int kk = 0; kk < 4; ++kk) {
            const uint4v p0 = *(const uint4v*)&sH1[w][lm][kk * 32 + lq * 8];
            const uint4v p1 = *(const uint4v*)&sH1[w][lm][kk * 32 + lq * 8 + 4];
            short8 aHh, aHl;
#pragma unroll
            for (int i = 0; i < 4; ++i) {
                aHh[i]     = (short)(p0[i] >> 16);
                aHl[i]     = (short)(p0[i] & 0xffffu);
                aHh[i + 4] = (short)(p1[i] >> 16);
                aHl[i + 4] = (short)(p1[i] & 0xffffu);
            }
#pragma unroll
            for (int nt = 0; nt < 8; ++nt) {
                const int fo = (((kk << 3) + nt) << 9) + (l << 3);
                const short8 bW = *(const short8*)&sW2h[fo];
                c2[nt] = mfma16(aHh, bW, c2[nt]);
                c2[nt] = mfma16(aHl, bW, c2[nt]);
                if constexpr (F32) {
                    const short8 bWl = *(const short8*)&sW2l[fo];
                    c2[nt] = mfma16(aHh, bWl, c2[nt]);
                }
            }
        }

        // ---- phase C: Cacc[f] += (H2+bf2) * y_j * y_k * mask ----
        int Jr[4], Kr[4]; float Mr[4];
#pragma unroll
        for (int r = 0; r < 4; ++r) {
            const int t = rowg + lq * 4 + r;
            Jr[r] = nbrj[t] & (AA - 1);
            Kr[r] = nbrk[t] & (AA - 1);
            Mr[r] = loadf<F32>(mask, t);
        }
#pragma unroll
        for (int r = 0; r < 4; ++r) {
            const float* pj = yb + Jr[r] * FF;
            const float* pk = yb + Kr[r] * FF;
#pragma unroll
            for (int nt = 0; nt < 8; ++nt) {
                const int f = nt * 16 + lm;
                const float h2 = c2[nt][r] + bf2v[nt];
                Cacc[nt] = fmaf(pj[f] * pk[f], h2 * Mr[r], Cacc[nt]);
            }
        }
    }

    // ---- reduce within wave (4 lanes per f), then across waves via LDS ----
#pragma unroll
    for (int nt = 0; nt < 8; ++nt) {
        float v = Cacc[nt];
        v += __shfl_xor(v, 16);
        v += __shfl_xor(v, 32);
        if (l < 16) sAccW[w][nt * 16 + lm] = v;
    }
    __syncthreads();
    if (tid < FF)
        sA[tid] = sAccW[0][tid] + sAccW[1][tid] + sAccW[2][tid] + sAccW[3][tid];
    __syncthreads();

    // ---- epilogue: out = ssp(acc @ Wout + bout) ----
    if (tid < FF) {
        float s = loadf<F32>(bout, tid);
#pragma unroll 8
        for (int f = 0; f < FF; ++f)
            s = fmaf(sA[f], loadf<F32>(Wout, f * FF + tid), s);
        const float r = ssp(s);
        if (F32) ((float*)out)[ba * FF + tid] = r;
        else     ((u16*)out)[ba * FF + tid]   = f2bf(r);
    }
}

extern "C" void kernel_launch(void* const* d_in, const int* in_sizes, int n_in,
                              void* d_out, int out_size, void* d_ws, size_t ws_size,
                              hipStream_t stream) {
    const void* x    = d_in[0];
    const void* r_ij = d_in[1];
    const void* mask = d_in[2];
    const void* Wf1  = d_in[3];
    const void* bf1  = d_in[4];
    const void* Wf2  = d_in[5];
    const void* bf2  = d_in[6];
    const void* Win  = d_in[7];
    const void* Wout = d_in[8];
    const void* bout = d_in[9];
    const int* nj    = (const int*)d_in[10];
    const int* nk    = (const int*)d_in[11];
    (void)d_ws; (void)ws_size; (void)in_sizes; (void)n_in; (void)out_size;

    k_detect<<<1, 64, 0, stream>>>(r_ij);
    k_in2f<false><<<BB * AA, 128, 0, stream>>>(x, Win);
    k_in2f<true ><<<BB * AA, 128, 0, stream>>>(x, Win);
    k_main<false><<<BB * AA, 256, 0, stream>>>(r_ij, mask, Wf1, bf1, Wf2, bf2,
                                               Wout, bout, nj, nk, d_out);
    k_main<true ><<<BB * AA, 256, 0, stream>>>(r_ij, mask, Wf1, bf1, Wf2, bf2,
                                               Wout, bout, nj, nk, d_out);
}

// Round 8
// 263.029 us; speedup vs baseline: 1.2086x; 1.2086x over previous
//
#include <hip/hip_runtime.h>
#include <hip/hip_bf16.h>

typedef unsigned short u16;
typedef __attribute__((ext_vector_type(8))) short short8;
typedef __bf16 bf16x8 __attribute__((ext_vector_type(8)));
typedef __attribute__((ext_vector_type(4))) float float4v;

#define BB 2
#define AA 512
#define TT 512
#define FF 128
#define NRBF 25

// static device scratch (no assumptions about ws_size)
__device__ float g_y[BB * AA * FF];
__device__ int   g_dtype;   // 0 = bf16 buffers, 1 = fp32 buffers

// ---------------- session ledger (keep: prevents re-exploring dead ends) ----
// PASS: lockstep 4-wave 3-barrier (r1,r3: 182us k_main, absmax 0.0625);
//       barrier-free 4-wave 100KB-LDS (r4: 246us, 1 blk/CU -- slower).
// FAIL (absmax 0.86-1.95, hi-only-precision signature, root cause NEVER
// identified): r2 multi-wave detect+(256,4); r5/r6 global weight-frag handoff;
// r7 512-thread reshape of r4. Do NOT revisit those axes without a targeted
// diagnostic; iterate within the proven lockstep skeleton instead.

__device__ __forceinline__ float bf2f(u16 u) {
    unsigned int v = ((unsigned int)u) << 16;
    return __builtin_bit_cast(float, v);
}
__device__ __forceinline__ u16 f2bf(float f) {
    unsigned int u = __builtin_bit_cast(unsigned int, f);
    u += 0x7fffu + ((u >> 16) & 1u);   // RNE
    return (u16)(u >> 16);
}
// Dekker-style split: v == bf2f(h) + bf2f(l) to ~2^-17 relative.
__device__ __forceinline__ void split2(float v, u16& h, u16& l) {
    h = f2bf(v);
    l = f2bf(v - bf2f(h));
}
template<bool F32>
__device__ __forceinline__ float loadf(const void* p, int i) {
    return F32 ? ((const float*)p)[i] : bf2f(((const u16*)p)[i]);
}
// shifted softplus via raw HW transcendentals (v_exp_f32 / v_log_f32)
__device__ __forceinline__ float ssp(float v) {
    float a = fabsf(v);
    float e = __builtin_amdgcn_exp2f(a * -1.44269504088896f);   // e^-|v|
    float l = __builtin_amdgcn_logf(1.0f + e);                  // log2(1+e^-|v|)
    return fmaxf(v, 0.0f) + fmaf(0.69314718055995f, l, -0.69314718055995f);
}
__device__ __forceinline__ float4v mfma16(short8 a, short8 b, float4v c) {
    return __builtin_amdgcn_mfma_f32_16x16x32_bf16(
        __builtin_bit_cast(bf16x8, a), __builtin_bit_cast(bf16x8, b), c, 0, 0, 0);
}

// ---- dtype detector (proven single-wave form, race-free; passed r3/r4) -----
__global__ __launch_bounds__(64) void k_detect(const void* r_raw) {
    const u16* p = (const u16*)r_raw;
    const int l = threadIdx.x;            // 0..63, one wave
    int sign = 0, zeros = 0;
#pragma unroll
    for (int i = 0; i < 8; ++i) {
        u16 v = p[2 * (l * 8 + i)];
        sign  += (v >> 15);
        zeros += (v == 0);
    }
#pragma unroll
    for (int off = 1; off < 64; off <<= 1) {
        sign  += __shfl_xor(sign, off);
        zeros += __shfl_xor(zeros, off);
    }
    if (l == 0) g_dtype = (sign || zeros > 400) ? 1 : 0;
}

// ---------------- kernel 1: y[b,a,f] = sum_i x[b,a,i] * Win[i,f]  (fp32 out) --
template<bool F32>
__global__ __launch_bounds__(128) void k_in2f(const void* __restrict__ x,
                                              const void* __restrict__ Win) {
    if (g_dtype != (F32 ? 1 : 0)) return;
    int ba = blockIdx.x;
    int o  = threadIdx.x;
    __shared__ float sx[FF];
    sx[o] = loadf<F32>(x, ba * FF + o);
    __syncthreads();
    float s = 0.f;
#pragma unroll 8
    for (int i = 0; i < FF; ++i)
        s = fmaf(sx[i], loadf<F32>(Win, i * FF + o), s);
    g_y[ba * FF + o] = s;
}

// ---------------- kernel 2: fused filter-net + gather-product + output -------
// ROUND-3 KERNEL (last solid pass: 182us k_main, absmax 0.0625) with ONE
// change: staging buffers (sR/sJ/sK/sM) are ping-ponged so the top-of-loop
// barrier is removed -> 2 barriers/tile instead of 3 (96 -> 64 total).
// Hazard proof for 2 barriers: sH1 write(t+1) vs read(t) ordered by syncA(t+1);
// sH1 write(t) vs read(t) by syncB(t); staging buffer b=t&1 is reused at t+2
// whose writes follow syncB(t+1), globally after all phase-C(t) reads of it.
// Numerics: split-bf16 MFMA (hi+lo Dekker split; Ah*Bh+Al*Bh+Ah*Bl), fp32-
// accurate filter GEMMs; absmax 0.0625 = bf16 OUTPUT rounding floor.
// For bf16 inputs (F32=false) r/Wf1/Wf2 are exact in bf16 -> lo terms vanish
// at compile time. __launch_bounds__(256,3): passed r3 at VGPR_Count 84.
template<bool F32>
__global__ __launch_bounds__(256, 3) void k_main(
    const void* __restrict__ r_ij, const void* __restrict__ mask,
    const void* __restrict__ Wf1,  const void* __restrict__ bf1,
    const void* __restrict__ Wf2,  const void* __restrict__ bf2_,
    const void* __restrict__ Wout, const void* __restrict__ bout,
    const int* __restrict__ nbrj,  const int* __restrict__ nbrk,
    void* __restrict__ out)
{
    if (g_dtype != (F32 ? 1 : 0)) return;
    const int ba  = blockIdx.x;           // (b,a) flat
    const int tid = threadIdx.x;
    const int w   = tid >> 6;             // wave 0..3 -> covers f in [32w,32w+32)
    const int l   = tid & 63;
    const int lm  = l & 15;               // col within frag
    const int lq  = l >> 4;               // quad

    __shared__ __align__(16) u16 sRh[2][16][40];    // ping-pong r tile (hi)
    __shared__ __align__(16) u16 sRl[2][16][40];    // lo residual (F32 path)
    __shared__ __align__(16) u16 sH1h[16][136];     // H1 hi, row pad +8
    __shared__ __align__(16) u16 sH1l[16][136];     // H1 lo residual
    __shared__ int   sJ[2][16];
    __shared__ int   sK[2][16];
    __shared__ float sM[2][16];
    __shared__ float sAcc[FF];

    // ---- preload constant B-fragments, split hi/lo (Wf1 padded to K=32) ----
    short8 fWf1h[2], fWf1l[2];
    short8 fWf2h[4][2], fWf2l[4][2];
    float  bf1v[2], bf2v[2];
#pragma unroll
    for (int q = 0; q < 2; ++q) {
        const int n = 32 * w + 16 * q + lm;
        short8 vh, vl;
#pragma unroll
        for (int j = 0; j < 8; ++j) {
            const int k = lq * 8 + j;
            float wv = (k < NRBF) ? loadf<F32>(Wf1, k * FF + n) : 0.f;
            u16 h, lo; split2(wv, h, lo);
            vh[j] = (short)h; vl[j] = (short)lo;
        }
        fWf1h[q] = vh;
        if (F32) fWf1l[q] = vl;
        bf1v[q] = loadf<F32>(bf1, n);
        bf2v[q] = loadf<F32>(bf2_, n);
#pragma unroll
        for (int kk = 0; kk < 4; ++kk) {
            short8 uh, ul;
#pragma unroll
            for (int j = 0; j < 8; ++j) {
                float wv = loadf<F32>(Wf2, (kk * 32 + lq * 8 + j) * FF + n);
                u16 h, lo; split2(wv, h, lo);
                uh[j] = (short)h; ul[j] = (short)lo;
            }
            fWf2h[kk][q] = uh;
            if (F32) fWf2l[kk][q] = ul;
        }
    }

    const float* yb = g_y + (ba >> 9) * (AA * FF);   // batch base of precomputed y
    const float4v zero = {0.f, 0.f, 0.f, 0.f};
    float acc[2] = {0.f, 0.f};

    for (int tile = 0; tile < TT / 16; ++tile) {
        const int t0 = tile * 16;
        const int b  = tile & 1;
        // ---- stage r tile split hi/lo (pad K 25->32) + neighbor/mask tile ----
        for (int e = tid; e < 16 * 32; e += 256) {
            const int tt = e >> 5, k = e & 31;
            float v = (k < NRBF) ? loadf<F32>(r_ij, (ba * TT + t0 + tt) * NRBF + k)
                                 : 0.f;
            u16 h, lo; split2(v, h, lo);
            sRh[b][tt][k] = h;
            if (F32) sRl[b][tt][k] = lo;
        }
        if (tid < 16) {
            sJ[b][tid] = nbrj[ba * TT + t0 + tid] & (AA - 1);
            sK[b][tid] = nbrk[ba * TT + t0 + tid] & (AA - 1);
            sM[b][tid] = loadf<F32>(mask, ba * TT + t0 + tid);
        }
        __syncthreads();   // syncA: stage visible; also orders sH1 w(t) after r(t-1)

        // ---- phase A: H1 = ssp(R @ Wf1 + bf1), split-bf16 ----
        short8 aRh = *(const short8*)((const char*)&sRh[b][0][0] + lm * 80 + lq * 16);
        float4v c1[2];
        c1[0] = mfma16(aRh, fWf1h[0], zero);
        c1[1] = mfma16(aRh, fWf1h[1], zero);
        if (F32) {
            short8 aRl = *(const short8*)((const char*)&sRl[b][0][0] + lm * 80 + lq * 16);
            c1[0] = mfma16(aRl, fWf1h[0], c1[0]);
            c1[1] = mfma16(aRl, fWf1h[1], c1[1]);
            c1[0] = mfma16(aRh, fWf1l[0], c1[0]);
            c1[1] = mfma16(aRh, fWf1l[1], c1[1]);
        }
#pragma unroll
        for (int q = 0; q < 2; ++q) {
            const int n = 32 * w + 16 * q + lm;
#pragma unroll
            for (int r = 0; r < 4; ++r) {
                const int m = lq * 4 + r;
                float h1 = ssp(c1[q][r] + bf1v[q]);
                u16 h, lo; split2(h1, h, lo);
                sH1h[m][n] = h;
                sH1l[m][n] = lo;
            }
        }
        __syncthreads();   // syncB: sH1 visible to all waves

        // ---- phase B: H2 = H1 @ Wf2, split-bf16 ----
        float4v c2[2] = {zero, zero};
#pragma unroll
        for (int kk = 0; kk < 4; ++kk) {
            short8 aHh = *(const short8*)((const char*)&sH1h[0][0] + lm * 272 + kk * 64 + lq * 16);
            short8 aHl = *(const short8*)((const char*)&sH1l[0][0] + lm * 272 + kk * 64 + lq * 16);
            c2[0] = mfma16(aHh, fWf2h[kk][0], c2[0]);
            c2[1] = mfma16(aHh, fWf2h[kk][1], c2[1]);
            c2[0] = mfma16(aHl, fWf2h[kk][0], c2[0]);
            c2[1] = mfma16(aHl, fWf2h[kk][1], c2[1]);
            if (F32) {
                c2[0] = mfma16(aHh, fWf2l[kk][0], c2[0]);
                c2[1] = mfma16(aHh, fWf2l[kk][1], c2[1]);
            }
        }

        // ---- phase C: acc[f] += (H2+bf2) * y_j * y_k * mask, sum over t ----
#pragma unroll
        for (int q = 0; q < 2; ++q) {
            const int n = 32 * w + 16 * q + lm;
            float a2 = 0.f;
#pragma unroll
            for (int r = 0; r < 4; ++r) {
                const int m  = lq * 4 + r;
                const float h2 = c2[q][r] + bf2v[q];
                const float yj = yb[sJ[b][m] * FF + n];
                const float yk = yb[sK[b][m] * FF + n];
                a2 = fmaf(h2 * yj, yk * sM[b][m], a2);
            }
            acc[q] += a2;
        }
        // no trailing barrier: next iteration stages into buffer b^1
    }

    // ---- reduce partial sums over the 4 quads, publish acc[0..127] ----
#pragma unroll
    for (int q = 0; q < 2; ++q) {
        float v = acc[q];
        v += __shfl_xor(v, 16);
        v += __shfl_xor(v, 32);
        if (lq == 0) sAcc[32 * w + 16 * q + lm] = v;
    }
    __syncthreads();

    // ---- epilogue: out = ssp(acc @ Wout + bout) ----
    if (tid < FF) {
        float s = loadf<F32>(bout, tid);
#pragma unroll 8
        for (int f = 0; f < FF; ++f)
            s = fmaf(sAcc[f], loadf<F32>(Wout, f * FF + tid), s);
        const float r = ssp(s);
        if (F32) ((float*)out)[ba * FF + tid] = r;
        else     ((u16*)out)[ba * FF + tid]   = f2bf(r);
    }
}

extern "C" void kernel_launch(void* const* d_in, const int* in_sizes, int n_in,
                              void* d_out, int out_size, void* d_ws, size_t ws_size,
                              hipStream_t stream) {
    const void* x    = d_in[0];
    const void* r_ij = d_in[1];
    const void* mask = d_in[2];
    const void* Wf1  = d_in[3];
    const void* bf1  = d_in[4];
    const void* Wf2  = d_in[5];
    const void* bf2  = d_in[6];
    const void* Win  = d_in[7];
    const void* Wout = d_in[8];
    const void* bout = d_in[9];
    const int* nj    = (const int*)d_in[10];
    const int* nk    = (const int*)d_in[11];
    (void)d_ws; (void)ws_size; (void)in_sizes; (void)n_in; (void)out_size;

    k_detect<<<1, 64, 0, stream>>>(r_ij);
    k_in2f<false><<<BB * AA, 128, 0, stream>>>(x, Win);
    k_in2f<true ><<<BB * AA, 128, 0, stream>>>(x, Win);
    k_main<false><<<BB * AA, 256, 0, stream>>>(r_ij, mask, Wf1, bf1, Wf2, bf2,
                                               Wout, bout, nj, nk, d_out);
    k_main<true ><<<BB * AA, 256, 0, stream>>>(r_ij, mask, Wf1, bf1, Wf2, bf2,
                                               Wout, bout, nj, nk, d_out);
}

// Round 9
// 234.991 us; speedup vs baseline: 1.3528x; 1.1193x over previous
//
#include <hip/hip_runtime.h>
#include <hip/hip_bf16.h>

typedef unsigned short u16;
typedef __attribute__((ext_vector_type(8))) short short8;
typedef __bf16 bf16x8 __attribute__((ext_vector_type(8)));
typedef __attribute__((ext_vector_type(4))) float float4v;
typedef __attribute__((ext_vector_type(4))) int int4v;

#define BB 2
#define AA 512
#define TT 512
#define FF 128
#define NRBF 25

// static device scratch (no assumptions about ws_size)
__device__ float g_y[BB * AA * FF];
__device__ int   g_dtype;   // 0 = bf16 buffers, 1 = fp32 buffers

// ---------------- session ledger (keep: prevents re-exploring dead ends) ----
// PASS: lockstep 4-wave 3-barrier (r1,r3: 182us k_main, absmax 0.0625);
//       2-barrier ping-pong (r8: 182us, absmax 0.375 -- no speedup, barriers
//       are NOT the cost; load latency on critical path is);
//       barrier-free 4-wave 100KB-LDS (r4: 246us, 1 blk/CU -- slower).
// FAIL (absmax 0.86-1.95, root cause NEVER identified): r2 multi-wave detect
//       +(256,4); r5/r6 global weight-frag handoff; r7 512-thread reshape.
// Live datapath is F32 (r4 counter: LDS_Block_Size matches F32 variant).
// Compiler drains vmcnt(0) at every __syncthreads -> cross-barrier register
// prefetch gets exactly one phase of cover; place issue points accordingly.

__device__ __forceinline__ float bf2f(u16 u) {
    unsigned int v = ((unsigned int)u) << 16;
    return __builtin_bit_cast(float, v);
}
__device__ __forceinline__ u16 f2bf(float f) {
    unsigned int u = __builtin_bit_cast(unsigned int, f);
    u += 0x7fffu + ((u >> 16) & 1u);   // RNE
    return (u16)(u >> 16);
}
// Dekker-style split: v == bf2f(h) + bf2f(l) to ~2^-17 relative.
__device__ __forceinline__ void split2(float v, u16& h, u16& l) {
    h = f2bf(v);
    l = f2bf(v - bf2f(h));
}
template<bool F32>
__device__ __forceinline__ float loadf(const void* p, int i) {
    return F32 ? ((const float*)p)[i] : bf2f(((const u16*)p)[i]);
}
// shifted softplus via raw HW transcendentals (v_exp_f32 / v_log_f32)
__device__ __forceinline__ float ssp(float v) {
    float a = fabsf(v);
    float e = __builtin_amdgcn_exp2f(a * -1.44269504088896f);   // e^-|v|
    float l = __builtin_amdgcn_logf(1.0f + e);                  // log2(1+e^-|v|)
    return fmaxf(v, 0.0f) + fmaf(0.69314718055995f, l, -0.69314718055995f);
}
__device__ __forceinline__ float4v mfma16(short8 a, short8 b, float4v c) {
    return __builtin_amdgcn_mfma_f32_16x16x32_bf16(
        __builtin_bit_cast(bf16x8, a), __builtin_bit_cast(bf16x8, b), c, 0, 0, 0);
}

// ---- dtype detector (proven single-wave form, race-free; passed r3/r4/r8) --
__global__ __launch_bounds__(64) void k_detect(const void* r_raw) {
    const u16* p = (const u16*)r_raw;
    const int l = threadIdx.x;            // 0..63, one wave
    int sign = 0, zeros = 0;
#pragma unroll
    for (int i = 0; i < 8; ++i) {
        u16 v = p[2 * (l * 8 + i)];
        sign  += (v >> 15);
        zeros += (v == 0);
    }
#pragma unroll
    for (int off = 1; off < 64; off <<= 1) {
        sign  += __shfl_xor(sign, off);
        zeros += __shfl_xor(zeros, off);
    }
    if (l == 0) g_dtype = (sign || zeros > 400) ? 1 : 0;
}

// ---------------- kernel 1: y[b,a,f] = sum_i x[b,a,i] * Win[i,f]  (fp32 out) --
template<bool F32>
__global__ __launch_bounds__(128) void k_in2f(const void* __restrict__ x,
                                              const void* __restrict__ Win) {
    if (g_dtype != (F32 ? 1 : 0)) return;
    int ba = blockIdx.x;
    int o  = threadIdx.x;
    __shared__ float sx[FF];
    sx[o] = loadf<F32>(x, ba * FF + o);
    __syncthreads();
    float s = 0.f;
#pragma unroll 8
    for (int i = 0; i < FF; ++i)
        s = fmaf(sx[i], loadf<F32>(Win, i * FF + o), s);
    g_y[ba * FF + o] = s;
}

// ---------------- kernel 2: fused filter-net + gather-product + output -------
// ROUND-8 SKELETON (passed; 2 barriers/tile, ping-pong staging) + SOFTWARE
// PIPELINING of the two latency legs that r8 proved to be the cost:
//  (1) phase-C gathers: sJ/sK/sM read + all 16 g_y loads issued right after
//      syncA, drained at syncB -> covered by phase A (~300cy) instead of
//      squeezed between syncB and use (~150cy of phase B).
//  (2) staging for tile t+1: global loads issued at top of iteration t into
//      registers; split+LDS-write at the bottom (same inter-barrier interval
//      as r8's staging writes -> identical hazard graph, proven safe).
// Both changes are same-wave register dataflow only; no new cross-wave
// orderings. Barriers, math, and fragment layouts byte-identical to r8.
// Numerics: split-bf16 MFMA (hi+lo Dekker; Ah*Bh+Al*Bh+Ah*Bl), fp32-accurate
// filter GEMMs. __launch_bounds__(256,3): 168-reg cap, est. demand ~120.
template<bool F32>
__global__ __launch_bounds__(256, 3) void k_main(
    const void* __restrict__ r_ij, const void* __restrict__ mask,
    const void* __restrict__ Wf1,  const void* __restrict__ bf1,
    const void* __restrict__ Wf2,  const void* __restrict__ bf2_,
    const void* __restrict__ Wout, const void* __restrict__ bout,
    const int* __restrict__ nbrj,  const int* __restrict__ nbrk,
    void* __restrict__ out)
{
    if (g_dtype != (F32 ? 1 : 0)) return;
    const int ba  = blockIdx.x;           // (b,a) flat
    const int tid = threadIdx.x;
    const int w   = tid >> 6;             // wave 0..3 -> covers f in [32w,32w+32)
    const int l   = tid & 63;
    const int lm  = l & 15;               // col within frag
    const int lq  = l >> 4;               // quad

    __shared__ __align__(16) u16 sRh[2][16][40];    // ping-pong r tile (hi)
    __shared__ __align__(16) u16 sRl[2][16][40];    // lo residual (F32 path)
    __shared__ __align__(16) u16 sH1h[16][136];     // H1 hi, row pad +8
    __shared__ __align__(16) u16 sH1l[16][136];     // H1 lo residual
    __shared__ __align__(16) int   sJ[2][16];
    __shared__ __align__(16) int   sK[2][16];
    __shared__ __align__(16) float sM[2][16];
    __shared__ float sAcc[FF];

    // ---- preload constant B-fragments, split hi/lo (Wf1 padded to K=32) ----
    short8 fWf1h[2], fWf1l[2];
    short8 fWf2h[4][2], fWf2l[4][2];
    float  bf1v[2], bf2v[2];
#pragma unroll
    for (int q = 0; q < 2; ++q) {
        const int n = 32 * w + 16 * q + lm;
        short8 vh, vl;
#pragma unroll
        for (int j = 0; j < 8; ++j) {
            const int k = lq * 8 + j;
            float wv = (k < NRBF) ? loadf<F32>(Wf1, k * FF + n) : 0.f;
            u16 h, lo; split2(wv, h, lo);
            vh[j] = (short)h; vl[j] = (short)lo;
        }
        fWf1h[q] = vh;
        if (F32) fWf1l[q] = vl;
        bf1v[q] = loadf<F32>(bf1, n);
        bf2v[q] = loadf<F32>(bf2_, n);
#pragma unroll
        for (int kk = 0; kk < 4; ++kk) {
            short8 uh, ul;
#pragma unroll
            for (int j = 0; j < 8; ++j) {
                float wv = loadf<F32>(Wf2, (kk * 32 + lq * 8 + j) * FF + n);
                u16 h, lo; split2(wv, h, lo);
                uh[j] = (short)h; ul[j] = (short)lo;
            }
            fWf2h[kk][q] = uh;
            if (F32) fWf2l[kk][q] = ul;
        }
    }

    const float* yb = g_y + (ba >> 9) * (AA * FF);   // batch base of precomputed y
    const float4v zero = {0.f, 0.f, 0.f, 0.f};
    float acc[2] = {0.f, 0.f};

    // staging element ids for this thread (2 elements of the 16x32 tile)
    const int tt0 = tid >> 5,          k0 = tid & 31;          // e = tid
    const int tt1 = (tid + 256) >> 5,  k1 = tid & 31;          // e = tid+256

    // ---- prologue: full stage of tile 0 into buffer 0 ----
    {
        float v0 = (k0 < NRBF) ? loadf<F32>(r_ij, (ba * TT + tt0) * NRBF + k0) : 0.f;
        float v1 = (k1 < NRBF) ? loadf<F32>(r_ij, (ba * TT + tt1) * NRBF + k1) : 0.f;
        u16 h, lo;
        split2(v0, h, lo); sRh[0][tt0][k0] = h; if (F32) sRl[0][tt0][k0] = lo;
        split2(v1, h, lo); sRh[0][tt1][k1] = h; if (F32) sRl[0][tt1][k1] = lo;
        if (tid < 16) {
            sJ[0][tid] = nbrj[ba * TT + tid] & (AA - 1);
            sK[0][tid] = nbrk[ba * TT + tid] & (AA - 1);
            sM[0][tid] = loadf<F32>(mask, ba * TT + tid);
        }
    }

    for (int tile = 0; tile < TT / 16; ++tile) {
        const int b = tile & 1;
        __syncthreads();   // syncA: staging for `tile` visible

        // ---- early: gather indices + issue all 16 g_y loads (drain @ syncB,
        //      covered by phase A) ----
        const int4v  Jv = *(const int4v*) &sJ[b][lq * 4];
        const int4v  Kv = *(const int4v*) &sK[b][lq * 4];
        const float4v Mv = *(const float4v*)&sM[b][lq * 4];
        float yjr[2][4], ykr[2][4];
#pragma unroll
        for (int q = 0; q < 2; ++q) {
            const int n = 32 * w + 16 * q + lm;
#pragma unroll
            for (int r = 0; r < 4; ++r) {
                yjr[q][r] = yb[Jv[r] * FF + n];
                ykr[q][r] = yb[Kv[r] * FF + n];
            }
        }

        // ---- early: issue staging loads for tile+1 into registers ----
        float pre0 = 0.f, pre1 = 0.f, preM = 0.f;
        int   preJ = 0,   preK = 0;
        if (tile + 1 < TT / 16) {
            const int t0n = (tile + 1) * 16;
            if (k0 < NRBF)
                pre0 = loadf<F32>(r_ij, (ba * TT + t0n + tt0) * NRBF + k0);
            if (k1 < NRBF)
                pre1 = loadf<F32>(r_ij, (ba * TT + t0n + tt1) * NRBF + k1);
            if (tid < 16) {
                preJ = nbrj[ba * TT + t0n + tid];
                preK = nbrk[ba * TT + t0n + tid];
                preM = loadf<F32>(mask, ba * TT + t0n + tid);
            }
        }

        // ---- phase A: H1 = ssp(R @ Wf1 + bf1), split-bf16 ----
        short8 aRh = *(const short8*)((const char*)&sRh[b][0][0] + lm * 80 + lq * 16);
        float4v c1[2];
        c1[0] = mfma16(aRh, fWf1h[0], zero);
        c1[1] = mfma16(aRh, fWf1h[1], zero);
        if (F32) {
            short8 aRl = *(const short8*)((const char*)&sRl[b][0][0] + lm * 80 + lq * 16);
            c1[0] = mfma16(aRl, fWf1h[0], c1[0]);
            c1[1] = mfma16(aRl, fWf1h[1], c1[1]);
            c1[0] = mfma16(aRh, fWf1l[0], c1[0]);
            c1[1] = mfma16(aRh, fWf1l[1], c1[1]);
        }
#pragma unroll
        for (int q = 0; q < 2; ++q) {
            const int n = 32 * w + 16 * q + lm;
#pragma unroll
            for (int r = 0; r < 4; ++r) {
                const int m = lq * 4 + r;
                float h1 = ssp(c1[q][r] + bf1v[q]);
                u16 h, lo; split2(h1, h, lo);
                sH1h[m][n] = h;
                sH1l[m][n] = lo;
            }
        }
        __syncthreads();   // syncB: sH1 visible (also drains prefetch loads)

        // ---- phase B: H2 = H1 @ Wf2, split-bf16 ----
        float4v c2[2] = {zero, zero};
#pragma unroll
        for (int kk = 0; kk < 4; ++kk) {
            short8 aHh = *(const short8*)((const char*)&sH1h[0][0] + lm * 272 + kk * 64 + lq * 16);
            short8 aHl = *(const short8*)((const char*)&sH1l[0][0] + lm * 272 + kk * 64 + lq * 16);
            c2[0] = mfma16(aHh, fWf2h[kk][0], c2[0]);
            c2[1] = mfma16(aHh, fWf2h[kk][1], c2[1]);
            c2[0] = mfma16(aHl, fWf2h[kk][0], c2[0]);
            c2[1] = mfma16(aHl, fWf2h[kk][1], c2[1]);
            if (F32) {
                c2[0] = mfma16(aHh, fWf2l[kk][0], c2[0]);
                c2[1] = mfma16(aHh, fWf2l[kk][1], c2[1]);
            }
        }

        // ---- phase C: acc[f] += (H2+bf2) * y_j * y_k * mask (regs only) ----
#pragma unroll
        for (int q = 0; q < 2; ++q) {
            float a2 = 0.f;
#pragma unroll
            for (int r = 0; r < 4; ++r) {
                const float h2 = c2[q][r] + bf2v[q];
                a2 = fmaf(h2 * yjr[q][r], ykr[q][r] * Mv[r], a2);
            }
            acc[q] += a2;
        }

        // ---- late: split + write prefetched staging into buffer b^1 ----
        // (same inter-barrier interval [syncB(t), syncA(t+1)) as r8's staging
        //  -> hazard graph identical to the passing r8 kernel)
        if (tile + 1 < TT / 16) {
            const int bn = b ^ 1;
            u16 h, lo;
            split2(pre0, h, lo); sRh[bn][tt0][k0] = h; if (F32) sRl[bn][tt0][k0] = lo;
            split2(pre1, h, lo); sRh[bn][tt1][k1] = h; if (F32) sRl[bn][tt1][k1] = lo;
            if (tid < 16) {
                sJ[bn][tid] = preJ & (AA - 1);
                sK[bn][tid] = preK & (AA - 1);
                sM[bn][tid] = preM;
            }
        }
    }

    // ---- reduce partial sums over the 4 quads, publish acc[0..127] ----
#pragma unroll
    for (int q = 0; q < 2; ++q) {
        float v = acc[q];
        v += __shfl_xor(v, 16);
        v += __shfl_xor(v, 32);
        if (lq == 0) sAcc[32 * w + 16 * q + lm] = v;
    }
    __syncthreads();

    // ---- epilogue: out = ssp(acc @ Wout + bout) ----
    if (tid < FF) {
        float s = loadf<F32>(bout, tid);
#pragma unroll 8
        for (int f = 0; f < FF; ++f)
            s = fmaf(sAcc[f], loadf<F32>(Wout, f * FF + tid), s);
        const float r = ssp(s);
        if (F32) ((float*)out)[ba * FF + tid] = r;
        else     ((u16*)out)[ba * FF + tid]   = f2bf(r);
    }
}

extern "C" void kernel_launch(void* const* d_in, const int* in_sizes, int n_in,
                              void* d_out, int out_size, void* d_ws, size_t ws_size,
                              hipStream_t stream) {
    const void* x    = d_in[0];
    const void* r_ij = d_in[1];
    const void* mask = d_in[2];
    const void* Wf1  = d_in[3];
    const void* bf1  = d_in[4];
    const void* Wf2  = d_in[5];
    const void* bf2  = d_in[6];
    const void* Win  = d_in[7];
    const void* Wout = d_in[8];
    const void* bout = d_in[9];
    const int* nj    = (const int*)d_in[10];
    const int* nk    = (const int*)d_in[11];
    (void)d_ws; (void)ws_size; (void)in_sizes; (void)n_in; (void)out_size;

    k_detect<<<1, 64, 0, stream>>>(r_ij);
    k_in2f<false><<<BB * AA, 128, 0, stream>>>(x, Win);
    k_in2f<true ><<<BB * AA, 128, 0, stream>>>(x, Win);
    k_main<false><<<BB * AA, 256, 0, stream>>>(r_ij, mask, Wf1, bf1, Wf2, bf2,
                                               Wout, bout, nj, nk, d_out);
    k_main<true ><<<BB * AA, 256, 0, stream>>>(r_ij, mask, Wf1, bf1, Wf2, bf2,
                                               Wout, bout, nj, nk, d_out);
}